// Round 1
// baseline (173.422 us; speedup 1.0000x reference)
//
#include <hip/hip_runtime.h>
#include <hip/hip_bf16.h>

#define BATCH    8192
#define NF       39      // num_fields
#define ED       64      // embed dim
#define RANK     32
#define DI0      2       // W0 dim_int
#define DI1      3       // W1 dim_int

// One block of 256 threads per batch sample.
// thread t: embed column i = t & 63; wave w = t >> 6 owns ranks [w*8, w*8+8).
// W accesses are wave-uniform -> readfirstlane forces s_load on the scalar pipe.
__global__ __launch_bounds__(256) void tfm_kernel(
    const int*   __restrict__ x,        // (B, NF)
    const float* __restrict__ embed,    // (100000, ED)
    const float* __restrict__ linw,     // (100000, 1)
    const float* __restrict__ lbias,    // (1,)
    const float* __restrict__ W0,       // (DI0, RANK, NF)
    const float* __restrict__ W1,       // (DI1, RANK, NF)
    float*       __restrict__ out)      // (B,)
{
    __shared__ float emb_s[NF][ED];     // 9984 B
    __shared__ int   xs[NF];
    __shared__ float lin_s;
    __shared__ float wsum[4];

    const int b = blockIdx.x;
    const int t = threadIdx.x;

    if (t < NF) xs[t] = x[b * NF + t];
    __syncthreads();

    // ---- gather embedding rows into LDS (coalesced, 4 rows per pass) ----
    const int col   = t & 63;
    const int rbase = t >> 6;
    for (int r = rbase; r < NF; r += 4) {
        emb_s[r][col] = embed[(size_t)xs[r] * ED + col];
    }

    // ---- linear term (wave 0) ----
    if (t < 64) {
        float v = (t < NF) ? linw[xs[t]] : 0.0f;
        for (int off = 32; off > 0; off >>= 1) v += __shfl_down(v, off, 64);
        if (t == 0) lin_s = v + lbias[0];
    }
    __syncthreads();

    // ---- pull my embedding column into registers ----
    const int i = col;
    float e[NF];
#pragma unroll
    for (int k = 0; k < NF; ++k) e[k] = emb_s[k][i];

    // ---- cross terms ----
    // jbase is wave-uniform; readfirstlane tells the compiler so W loads scalarize.
    const int jbase = __builtin_amdgcn_readfirstlane((t >> 6) * 8);
    float acc = 0.0f;

#pragma unroll
    for (int jj = 0; jj < 8; ++jj) {
        const int j = jbase + jj;

        // W0: product over l = 0..1
        {
            const float* w0 = W0 + (0 * RANK + j) * NF;
            const float* w1 = W0 + (1 * RANK + j) * NF;
            float d0 = 0.0f, d1 = 0.0f;
#pragma unroll
            for (int k = 0; k < NF; ++k) {
                d0 = fmaf(w0[k], e[k], d0);
                d1 = fmaf(w1[k], e[k], d1);
            }
            acc = fmaf(d0, d1, acc);
        }
        // W1: product over l = 0..2
        {
            const float* u0 = W1 + (0 * RANK + j) * NF;
            const float* u1 = W1 + (1 * RANK + j) * NF;
            const float* u2 = W1 + (2 * RANK + j) * NF;
            float s0 = 0.0f, s1 = 0.0f, s2 = 0.0f;
#pragma unroll
            for (int k = 0; k < NF; ++k) {
                s0 = fmaf(u0[k], e[k], s0);
                s1 = fmaf(u1[k], e[k], s1);
                s2 = fmaf(u2[k], e[k], s2);
            }
            acc = fmaf(s0 * s1, s2, acc);
        }
    }

    // ---- reduce 256 partials ----
    for (int off = 32; off > 0; off >>= 1) acc += __shfl_down(acc, off, 64);
    if ((t & 63) == 0) wsum[t >> 6] = acc;
    __syncthreads();
    if (t == 0) out[b] = wsum[0] + wsum[1] + wsum[2] + wsum[3] + lin_s;
}

extern "C" void kernel_launch(void* const* d_in, const int* in_sizes, int n_in,
                              void* d_out, int out_size, void* d_ws, size_t ws_size,
                              hipStream_t stream) {
    const int*   x     = (const int*)  d_in[0];
    const float* embed = (const float*)d_in[1];
    const float* linw  = (const float*)d_in[2];
    const float* lbias = (const float*)d_in[3];
    const float* W0    = (const float*)d_in[4];
    const float* W1    = (const float*)d_in[5];
    float*       out   = (float*)d_out;

    tfm_kernel<<<BATCH, 256, 0, stream>>>(x, embed, linw, lbias, W0, W1, out);
}

// Round 2
// 139.489 us; speedup vs baseline: 1.2433x; 1.2433x over previous
//
#include <hip/hip_runtime.h>
#include <hip/hip_bf16.h>

#define BATCH    8192
#define NF       39      // num_fields
#define ED       64      // embed dim
#define RANK     32
#define NROWS    160     // 2*32 (W0) + 3*32 (W1) rank-rows
#define NKK      20      // ceil(NF/2) f16-pairs per row (k=39 is zero pad)
#define EROW     42      // LDS row stride in halves: 21 dwords, gcd(21,32)=1 -> conflict-free

typedef _Float16 f16x2 __attribute__((ext_vector_type(2)));

static __device__ __forceinline__ float fdot2(f16x2 a, f16x2 b, float c) {
#if __has_builtin(__builtin_amdgcn_fdot2)
    return __builtin_amdgcn_fdot2(a, b, c, false);
#else
    return fmaf((float)a.y, (float)b.y, fmaf((float)a.x, (float)b.x, c));
#endif
}

// ---- prepass: convert W0/W1 fp32 -> f16x2 in ws, layout [kk][row] ----
// row = l*32 + j for W0 (l=0,1); row = 64 + l*32 + j for W1 (l=0..2).
// k = 2*kk, 2*kk+1; k >= 39 is zeroed.
__global__ void prep_w(const float* __restrict__ W0,
                       const float* __restrict__ W1,
                       f16x2* __restrict__ wsW) {
    int d = blockIdx.x * 256 + threadIdx.x;
    if (d >= NKK * NROWS) return;
    int kk  = d / NROWS;
    int row = d % NROWS;
    int k0 = 2 * kk, k1 = k0 + 1;
    const float* p;
    if (row < 64) { int l = row >> 5, j = row & 31; p = W0 + (l * RANK + j) * NF; }
    else          { int r = row - 64; int l = r >> 5, j = r & 31; p = W1 + (l * RANK + j) * NF; }
    float a = (k0 < NF) ? p[k0] : 0.0f;
    float b = (k1 < NF) ? p[k1] : 0.0f;
    f16x2 h; h.x = (_Float16)a; h.y = (_Float16)b;
    wsW[kk * NROWS + row] = h;   // [kk][row]
}

// ---- main: one block (256 thr) per sample ----
// thread: i = t&63 (embed col), wave = t>>6 owns ranks [w*8, w*8+8).
// k-outer loop: ek read once, 40 accumulators live in VGPRs, W via scalar loads.
__global__ __launch_bounds__(256) void tfm_kernel(
    const int*   __restrict__ x,        // (B, NF)
    const float* __restrict__ embed,    // (100000, ED)
    const float* __restrict__ linw,     // (100000, 1)
    const float* __restrict__ lbias,    // (1,)
    const f16x2* __restrict__ wsW,      // [NKK][NROWS]
    float*       __restrict__ out)      // (B,)
{
    __shared__ _Float16 emb_h[ED][EROW];
    __shared__ int   xs[NF];
    __shared__ float lin_s;
    __shared__ float wsum[4];

    const int b = blockIdx.x;
    const int t = threadIdx.x;

    if (t < NF) xs[t] = x[b * NF + t];
    __syncthreads();

    // gather + f16 convert into LDS, layout [i][k] (k contiguous per column)
    const int col   = t & 63;
    const int rbase = t >> 6;
    for (int r = rbase; r < NF; r += 4) {
        emb_h[col][r] = (_Float16)embed[(size_t)xs[r] * ED + col];
    }
    if (t < ED) emb_h[t][NF] = (_Float16)0.0f;   // zero the k=39 pad

    // linear term (wave 0), fp32
    if (t < 64) {
        float v = (t < NF) ? linw[xs[t]] : 0.0f;
        for (int off = 32; off > 0; off >>= 1) v += __shfl_down(v, off, 64);
        if (t == 0) lin_s = v + lbias[0];
    }
    __syncthreads();

    const int jbase = __builtin_amdgcn_readfirstlane((t >> 6) * 8);

    float acc[8][5];
#pragma unroll
    for (int jj = 0; jj < 8; ++jj)
#pragma unroll
        for (int l = 0; l < 5; ++l) acc[jj][l] = 0.0f;

    // my column's f16-pairs; addr = col*84 + kk*4, stride 21 dwords -> 2-way (free)
    const f16x2* erow = (const f16x2*)&emb_h[col][0];

    for (int kk = 0; kk < NKK; ++kk) {
        const f16x2 ek = erow[kk];
        const f16x2* wrow = wsW + kk * NROWS;   // wave-uniform
#pragma unroll
        for (int jj = 0; jj < 8; ++jj) {
            const int j = jbase + jj;
            acc[jj][0] = fdot2(wrow[      j], ek, acc[jj][0]);  // W0 l=0
            acc[jj][1] = fdot2(wrow[ 32 + j], ek, acc[jj][1]);  // W0 l=1
            acc[jj][2] = fdot2(wrow[ 64 + j], ek, acc[jj][2]);  // W1 l=0
            acc[jj][3] = fdot2(wrow[ 96 + j], ek, acc[jj][3]);  // W1 l=1
            acc[jj][4] = fdot2(wrow[128 + j], ek, acc[jj][4]);  // W1 l=2
        }
    }

    // epilogue: prod over l, sum over my 8 ranks
    float s = 0.0f;
#pragma unroll
    for (int jj = 0; jj < 8; ++jj) {
        s += acc[jj][0] * acc[jj][1];
        s += acc[jj][2] * acc[jj][3] * acc[jj][4];
    }

    for (int off = 32; off > 0; off >>= 1) s += __shfl_down(s, off, 64);
    if ((t & 63) == 0) wsum[t >> 6] = s;
    __syncthreads();
    if (t == 0) out[b] = wsum[0] + wsum[1] + wsum[2] + wsum[3] + lin_s;
}

extern "C" void kernel_launch(void* const* d_in, const int* in_sizes, int n_in,
                              void* d_out, int out_size, void* d_ws, size_t ws_size,
                              hipStream_t stream) {
    const int*   x     = (const int*)  d_in[0];
    const float* embed = (const float*)d_in[1];
    const float* linw  = (const float*)d_in[2];
    const float* lbias = (const float*)d_in[3];
    const float* W0    = (const float*)d_in[4];
    const float* W1    = (const float*)d_in[5];
    float*       out   = (float*)d_out;
    f16x2*       wsW   = (f16x2*)d_ws;          // 160*20*4 B = 12.8 KB

    prep_w<<<(NKK * NROWS + 255) / 256, 256, 0, stream>>>(W0, W1, wsW);
    tfm_kernel<<<BATCH, 256, 0, stream>>>(x, embed, linw, lbias, wsW, out);
}

// Round 3
// 95.416 us; speedup vs baseline: 1.8175x; 1.4619x over previous
//
#include <hip/hip_runtime.h>
#include <hip/hip_bf16.h>

#define BATCH    8192
#define NF       39      // num_fields
#define ED       64      // embed dim
#define RANK     32
#define NL       5       // 2 (W0) + 3 (W1) l-slices
#define KP       48      // k padded to 3 chunks of 16
#define KH       56      // LDS k-stride in halves: 112 B, 16B-aligned
#define SPW      4       // samples per wave

typedef _Float16 half8  __attribute__((ext_vector_type(8)));
typedef float    f32x16 __attribute__((ext_vector_type(16)));

// One wave = 4 samples, fully wave-private (no block barriers).
// Per sample: gather 39 embed rows -> f16 -> LDS [i][k]; then per i-tile (2):
// 3 ds_read_b128 B-frags x 5 register W-frags -> 15 mfma_f32_32x32x16_f16;
// epilogue: prod over l, sum over all (j,i) -> one scalar per sample.
// C/D layout irrelevant (we sum the whole tile; tiles never straddle samples).
__global__ __launch_bounds__(256, 2) void tfm_kernel(
    const int*   __restrict__ x,        // (B, NF)
    const float* __restrict__ embed,    // (100000, ED)
    const float* __restrict__ linw,     // (100000, 1)
    const float* __restrict__ lbias,    // (1,)
    const float* __restrict__ W0,       // (2, RANK, NF)
    const float* __restrict__ W1,       // (3, RANK, NF)
    float*       __restrict__ out)      // (B,)
{
    __shared__ __align__(16) _Float16 Es[4][ED][KH];   // 28672 B, wave-private slices

    const int t    = threadIdx.x;
    const int lane = t & 63;
    const int w    = t >> 6;                   // wave within block
    const int gw   = blockIdx.x * 4 + w;       // global wave id
    const int s0   = gw * SPW;

    const float bias = lbias[0];

    // ---- per-sample x vectors, issued up front ----
    int xv[SPW];
#pragma unroll
    for (int si = 0; si < SPW; ++si)
        xv[si] = (lane < NF) ? x[(s0 + si) * NF + lane] : 0;

    // ---- W fragments, register-resident (15 x half8 = 60 VGPRs) ----
    // A-frag map: row j = lane&31, k = kc*16 + (lane>>5)*8 + e
    const int j  = lane & 31;
    const int kh = lane >> 5;
    half8 wf[NL][3];
#pragma unroll
    for (int l = 0; l < NL; ++l) {
        const float* base = (l < 2) ? (W0 + (l * RANK + j) * NF)
                                    : (W1 + ((l - 2) * RANK + j) * NF);
#pragma unroll
        for (int kc = 0; kc < 3; ++kc) {
#pragma unroll
            for (int e = 0; e < 8; ++e) {
                int k = kc * 16 + kh * 8 + e;
                wf[l][kc][e] = (k < NF) ? (_Float16)base[k] : (_Float16)0.0f;
            }
        }
    }

#pragma unroll
    for (int si = 0; si < SPW; ++si) {
        const int s = s0 + si;

        // linear-term gather (issued early, consumed at the end)
        float lv = 0.0f;
        if (lane < NF) lv = linw[xv[si]];

        // ---- gather 39 rows; each wave-instr loads one full 256B row ----
        float r[NF];
#pragma unroll
        for (int k = 0; k < NF; ++k) {
            int xi = __builtin_amdgcn_readlane(xv[si], k);   // uniform -> SGPR base
            const float* rowp = embed + (size_t)xi * ED;
            r[k] = rowp[lane];
        }

        // ---- pack f16, write LDS [i=lane][k] as 6 x b128 ----
#pragma unroll
        for (int c6 = 0; c6 < 6; ++c6) {
            half8 hh;
#pragma unroll
            for (int e = 0; e < 8; ++e) {
                int k = c6 * 8 + e;
                hh[e] = (k < NF) ? (_Float16)r[k] : (_Float16)0.0f;
            }
            *(half8*)&Es[w][lane][c6 * 8] = hh;
        }
        // wave-private LDS: compiler's lgkmcnt ordering suffices, no barrier

        float ssum = lv;

        // ---- 2 i-tiles of 32 cols (each tile entirely within sample s) ----
#pragma unroll
        for (int tile = 0; tile < 2; ++tile) {
            f32x16 acc[NL];
#pragma unroll
            for (int l = 0; l < NL; ++l)
#pragma unroll
                for (int e = 0; e < 16; ++e) acc[l][e] = 0.0f;

            const int c = tile * 32 + (lane & 31);
#pragma unroll
            for (int kc = 0; kc < 3; ++kc) {
                half8 bf = *(const half8*)&Es[w][c][kc * 16 + kh * 8];
#pragma unroll
                for (int l = 0; l < NL; ++l)
                    acc[l] = __builtin_amdgcn_mfma_f32_32x32x16_f16(
                                 wf[l][kc], bf, acc[l], 0, 0, 0);
            }
            // product over l, sum every element (C/D layout-agnostic)
#pragma unroll
            for (int e = 0; e < 16; ++e) {
                ssum += acc[0][e] * acc[1][e];
                ssum += acc[2][e] * acc[3][e] * acc[4][e];
            }
        }

        // ---- 64-lane reduce, lane 0 writes ----
#pragma unroll
        for (int off = 32; off > 0; off >>= 1) ssum += __shfl_down(ssum, off, 64);
        if (lane == 0) out[s] = ssum + bias;
    }
}

extern "C" void kernel_launch(void* const* d_in, const int* in_sizes, int n_in,
                              void* d_out, int out_size, void* d_ws, size_t ws_size,
                              hipStream_t stream) {
    const int*   x     = (const int*)  d_in[0];
    const float* embed = (const float*)d_in[1];
    const float* linw  = (const float*)d_in[2];
    const float* lbias = (const float*)d_in[3];
    const float* W0    = (const float*)d_in[4];
    const float* W1    = (const float*)d_in[5];
    float*       out   = (float*)d_out;

    // 512 blocks x 4 waves x 4 samples = 8192
    tfm_kernel<<<BATCH / (4 * SPW), 256, 0, stream>>>(x, embed, linw, lbias, W0, W1, out);
}